// Round 12
// baseline (223.808 us; speedup 1.0000x reference)
//
#include <hip/hip_runtime.h>
#include <hip/hip_bf16.h>
#include <math.h>

#define F_IN   128
#define F_OUT  64
#define CHUNK  4096        // edges per bin block
#define BINTHREADS 1024    // bin block size (16 waves/block; round-11 win)
#define EPT    4           // edges per thread (CHUNK/BINTHREADS)
#define BSH    7           // bucket shift: 128 dsts per coarse bucket
#define CAP    3072        // per-bucket capacity (validated rounds 5-11)
#define NBCA   1024        // bucket array alignment
#define SMEM_SZ 33024      // union: sort 25KB | gemm 32.25KB

typedef short bf16x8 __attribute__((ext_vector_type(8)));
typedef float f32x4  __attribute__((ext_vector_type(4)));

__device__ __forceinline__ unsigned short f2bf(float f) {
    union { float f; unsigned int i; } c; c.f = f;
    unsigned int r = c.i + 0x7FFFu + ((c.i >> 16) & 1u);   // RNE
    return (unsigned short)(r >> 16);
}
__device__ __forceinline__ unsigned int pk2bf(float a, float b) {
    __hip_bfloat162 p = __float22bfloat162_rn(make_float2(a, b));  // v_cvt_pk_bf16_f32
    union { __hip_bfloat162 h; unsigned int u; } c; c.h = p; return c.u;
}
__device__ __forceinline__ float u_lo(unsigned int u) {
    union { unsigned int i; float f; } c; c.i = u << 16; return c.f;
}
__device__ __forceinline__ float u_hi(unsigned int u) {
    union { unsigned int i; float f; } c; c.i = u & 0xFFFF0000u; return c.f;
}

// ---- K1: front = binning (round-11 structure, 16 waves/block) + per-dst
// in-degree via fire-and-forget global atomics (benign: 100k addrs, chain~16,
// no value returned -> pipelined). deg available before the sort||gemm node.
__global__ __launch_bounds__(BINTHREADS) void k_front(
    const int* __restrict__ src, const int* __restrict__ dst, int E,
    unsigned int* __restrict__ bcnt, int* __restrict__ deg,
    unsigned int* __restrict__ entries, int NBC) {
    __shared__ int hist[NBCA];
    __shared__ int gbase[NBCA];
    __shared__ int lcur[NBCA];
    const int tid = threadIdx.x;
    const int e0 = blockIdx.x * CHUNK;

    for (int c = tid; c < NBCA; c += BINTHREADS) { hist[c] = 0; lcur[c] = 0; }
    __syncthreads();

    int dv[EPT], sv[EPT];
    #pragma unroll
    for (int j = 0; j < EPT; ++j) {
        int e = e0 + j * BINTHREADS + tid;
        if (e < E) {
            dv[j] = dst[e];
            sv[j] = src[e];
            atomicAdd(&hist[dv[j] >> BSH], 1);     // LDS atomic
            atomicAdd(&deg[dv[j]], 1);             // global fire-and-forget
        } else dv[j] = -1;
    }
    __syncthreads();

    for (int c = tid; c < NBC; c += BINTHREADS) {
        int h = hist[c];
        gbase[c] = h ? (int)atomicAdd(&bcnt[c], (unsigned int)h) : 0;
    }
    __syncthreads();

    #pragma unroll
    for (int j = 0; j < EPT; ++j) {
        if (dv[j] >= 0) {
            int b = dv[j] >> BSH;
            int r = atomicAdd(&lcur[b], 1);        // LDS atomic
            entries[b * CAP + gbase[b] + r] =
                ((unsigned int)(dv[j] & 127) << 24) | (unsigned int)sv[j];
        }
    }
}

// ---- K2: heterogeneous node: blocks [0,NBC) = per-bucket counting sort;
// blocks [NBC, NBC+NT) = MFMA GEMM tile. gemm reads deg[] directly (identical
// integers to od.y) so it has no dependency on sort; the two co-reside.
__global__ __launch_bounds__(256) void k_sortgemm(
    const unsigned int* __restrict__ entries, const unsigned int* __restrict__ bcnt,
    const int* __restrict__ deg,
    const float* __restrict__ x, const float* __restrict__ W,
    int2* __restrict__ od, unsigned int* __restrict__ srcs,
    unsigned short* __restrict__ g, int N, int NBC) {
    __shared__ __align__(16) char smem[SMEM_SZ];
    const int tid = threadIdx.x;

    if (blockIdx.x < NBC) {
        // ---------------- sort part (25 KB of smem) ----------------
        unsigned int* le = (unsigned int*)smem;          // [CAP]
        unsigned int* ls = le + CAP;                     // [CAP]
        int* hist = (int*)(ls + CAP);                    // [128]
        int* curs = hist + 128;                          // [128]
        const int b = blockIdx.x;
        const int base = b * CAP;
        const int cnt = min((int)bcnt[b], CAP);

        if (tid < 128) hist[tid] = 0;
        __syncthreads();
        for (int i = tid; i < cnt; i += 256) {
            unsigned int v = entries[base + i];
            le[i] = v;
            atomicAdd(&hist[v >> 24], 1);
        }
        __syncthreads();

        int cntv = (tid < 128) ? hist[tid] : 0;
        if (tid < 128) curs[tid] = cntv;
        __syncthreads();
        for (int off = 1; off < 128; off <<= 1) {
            int t = (tid >= off && tid < 128) ? curs[tid - off] : 0;
            __syncthreads();
            if (tid < 128) curs[tid] += t;
            __syncthreads();
        }
        if (tid < 128) {
            int excl = curs[tid] - cntv;
            int d = (b << BSH) + tid;
            if (d < N) od[d] = make_int2(base + excl, cntv);
            curs[tid] = excl;
        }
        __syncthreads();

        for (int i = tid; i < cnt; i += 256) {
            unsigned int v = le[i];
            int p = atomicAdd(&curs[v >> 24], 1);
            ls[p] = (v & 0xFFFFFFu) << 7;
        }
        __syncthreads();

        for (int i = tid; i < cnt; i += 256)
            srcs[base + i] = ls[i];
        return;
    }

    // ---------------- gemm part (32.25 KB of smem) ----------------
    unsigned short* xs  = (unsigned short*)smem;         // [64*F_IN]
    unsigned short* Wsh = xs + 64 * F_IN;                // [F_OUT*F_IN]
    float* dinvs = (float*)(Wsh + F_OUT * F_IN);         // [64]
    const int row0 = (blockIdx.x - NBC) * 64;

    {
        const float4* W4 = (const float4*)W;
        #pragma unroll
        for (int t = 0; t < 8; ++t) {
            int idx = t * 256 + tid;
            float4 v = W4[idx];
            *(uint2*)&Wsh[idx * 4] = make_uint2(pk2bf(v.x, v.y), pk2bf(v.z, v.w));
        }
    }
    {
        const float4* x4 = (const float4*)x;
        #pragma unroll
        for (int t = 0; t < 8; ++t) {
            int idx = t * 256 + tid;
            int r = idx >> 5;
            int grow = row0 + r;
            float4 v = make_float4(0.f, 0.f, 0.f, 0.f);
            if (grow < N) v = x4[(size_t)grow * 32 + (idx & 31)];
            *(uint2*)&xs[idx * 4] = make_uint2(pk2bf(v.x, v.y), pk2bf(v.z, v.w));
        }
    }
    if (tid < 64) {
        int grow = row0 + tid;
        float dvv = 1.0f;
        if (grow < N) dvv = rsqrtf((float)deg[grow] + 1.0f);
        dinvs[tid] = dvv;
    }
    __syncthreads();

    const int lane = tid & 63;
    const int wave = tid >> 6;
    const int m = lane & 15;
    const int q = lane >> 4;
    const int r0 = wave * 16;

    bf16x8 a[4];
    #pragma unroll
    for (int ks = 0; ks < 4; ++ks)
        a[ks] = *(const bf16x8*)&xs[(r0 + m) * F_IN + ks * 32 + q * 8];

    f32x4 acc[4] = {{0,0,0,0},{0,0,0,0},{0,0,0,0},{0,0,0,0}};
    #pragma unroll
    for (int ct = 0; ct < 4; ++ct) {
        #pragma unroll
        for (int ks = 0; ks < 4; ++ks) {
            bf16x8 b = *(const bf16x8*)&Wsh[(ct * 16 + m) * F_IN + ks * 32 + q * 8];
            acc[ct] = __builtin_amdgcn_mfma_f32_16x16x32_bf16(a[ks], b, acc[ct], 0, 0, 0);
        }
    }

    float dvv[4];
    #pragma unroll
    for (int reg = 0; reg < 4; ++reg)
        dvv[reg] = dinvs[r0 + q * 4 + reg];
    #pragma unroll
    for (int ct = 0; ct < 4; ++ct) {
        #pragma unroll
        for (int reg = 0; reg < 4; ++reg) {
            int grow = row0 + r0 + q * 4 + reg;
            // grow == N writes the zero sentinel row (acc==0 there)
            if (grow <= N)
                g[(size_t)grow * F_OUT + ct * 16 + m] = f2bf(acc[ct][reg] * dvv[reg]);
        }
    }
}

// ---- K3: pull aggregation + fused epilogue (exact round-6/8 body, 35.6 us) ----
__global__ __launch_bounds__(256) void k_pull(
    const unsigned short* __restrict__ g, const int2* __restrict__ od,
    const unsigned int* __restrict__ srcs,
    const float* __restrict__ b_conv, const float* __restrict__ W_lin,
    const float* __restrict__ b_lin, float* __restrict__ out, int N) {
    const int lane = threadIdx.x & 63;
    const int li   = lane & 15;        // feature-quad index
    const int grp  = lane >> 4;        // edge group 0..3
    const int wave   = (blockIdx.x * blockDim.x + threadIdx.x) >> 6;
    const int nwaves = (gridDim.x * blockDim.x) >> 6;

    const float4 wl = ((const float4*)W_lin)[li];
    const float4 bb = ((const float4*)b_conv)[li];
    const float  bl = b_lin[0];
    const char* gb = (const char*)g;
    const unsigned int lioff = ((unsigned int)li) << 3;   // byte offset in row
    const unsigned int sentb = ((unsigned int)N) << 7;    // zero-row byte offset

    for (int i = wave; i < N; i += nwaves) {
        int2 odv = od[i];
        int e0 = __builtin_amdgcn_readfirstlane(odv.x);
        int dg = __builtin_amdgcn_readfirstlane(odv.y);
        int full = dg >> 4;
        int rem  = dg & 15;

        // self loop: group 0 only (others add 0)
        uint2 us = *(const uint2*)(gb + ((((unsigned int)i) << 7) | lioff));
        float4 acc;
        acc.x = grp ? 0.f : u_lo(us.x);
        acc.y = grp ? 0.f : u_hi(us.x);
        acc.z = grp ? 0.f : u_lo(us.y);
        acc.w = grp ? 0.f : u_hi(us.y);

        const unsigned int* sp = srcs + e0 + grp;   // group-interleaved list
        for (int it = 0; it < full; ++it) {
            unsigned int off[4];
            #pragma unroll
            for (int t = 0; t < 4; ++t)
                off[t] = sp[4 * t];                 // immediate offsets 0,4,8,12
            uint2 u[4];
            #pragma unroll
            for (int t = 0; t < 4; ++t)
                u[t] = *(const uint2*)(gb + (size_t)(off[t] | lioff));
            #pragma unroll
            for (int t = 0; t < 4; ++t) {
                acc.x += u_lo(u[t].x); acc.y += u_hi(u[t].x);
                acc.z += u_lo(u[t].y); acc.w += u_hi(u[t].y);
            }
            sp += 16;
        }
        if (rem) {                                  // wave-uniform branch
            unsigned int off[4];
            #pragma unroll
            for (int t = 0; t < 4; ++t) {
                unsigned int o = sp[4 * t];         // in-bounds load, may be junk
                off[t] = (4 * t + grp < rem) ? o : sentb;   // junk never addressed
            }
            uint2 u[4];
            #pragma unroll
            for (int t = 0; t < 4; ++t)
                u[t] = *(const uint2*)(gb + (size_t)(off[t] | lioff));
            #pragma unroll
            for (int t = 0; t < 4; ++t) {
                acc.x += u_lo(u[t].x); acc.y += u_hi(u[t].x);
                acc.z += u_lo(u[t].y); acc.w += u_hi(u[t].y);
            }
        }

        // sum across the 4 edge groups (lane bits 4,5)
        #pragma unroll
        for (int mk = 16; mk <= 32; mk <<= 1) {
            acc.x += __shfl_xor(acc.x, mk, 64);
            acc.y += __shfl_xor(acc.y, mk, 64);
            acc.z += __shfl_xor(acc.z, mk, 64);
            acc.w += __shfl_xor(acc.w, mk, 64);
        }

        float dinv = rsqrtf((float)dg + 1.0f);
        float r0 = fmaxf(acc.x * dinv + bb.x, 0.f);
        float r1 = fmaxf(acc.y * dinv + bb.y, 0.f);
        float r2 = fmaxf(acc.z * dinv + bb.z, 0.f);
        float r3 = fmaxf(acc.w * dinv + bb.w, 0.f);
        float t = r0 * wl.x + r1 * wl.y + r2 * wl.z + r3 * wl.w;
        #pragma unroll
        for (int mk = 1; mk <= 8; mk <<= 1)         // reduce over li (bits 0..3)
            t += __shfl_xor(t, mk, 64);
        if (lane == 0)
            out[i] = 1.0f / (1.0f + expf(-(t + bl)));
    }
}

extern "C" void kernel_launch(void* const* d_in, const int* in_sizes, int n_in,
                              void* d_out, int out_size, void* d_ws, size_t ws_size,
                              hipStream_t stream) {
    const float* x      = (const float*)d_in[0];
    const int*   ei     = (const int*)d_in[1];
    const float* W_conv = (const float*)d_in[2];
    const float* b_conv = (const float*)d_in[3];
    const float* W_lin  = (const float*)d_in[4];
    const float* b_lin  = (const float*)d_in[5];

    const int N = in_sizes[0] / F_IN;     // 100000
    const int E = in_sizes[1] / 2;        // 1600000
    const int* src = ei;
    const int* dst = ei + E;
    float* out = (float*)d_out;

    const int NBC  = (N + 127) >> BSH;          // 782 coarse buckets
    const int NBLK = (E + CHUNK - 1) / CHUNK;   // 391 front blocks
    const int NT   = (N + 64) / 64;             // 1564 gemm tiles (covers row N)
    const int Na   = NBC << BSH;

    // workspace layout (4-byte units), ~33 MB
    unsigned int* bcnt = (unsigned int*)d_ws;                    // [NBCA]  (memset 0)
    int* deg = (int*)(bcnt + NBCA);                              // [Na]    (memset 0)
    int2* od = (int2*)(deg + Na);                                // [Na]
    unsigned int* entries = (unsigned int*)((int*)od + 2 * Na);  // [NBC*CAP]
    unsigned int* srcs = entries + (size_t)NBC * CAP;            // [NBC*CAP + 64]
    char* graw = (char*)(srcs + (size_t)NBC * CAP + 64);
    unsigned short* g = (unsigned short*)(((size_t)graw + 255) & ~(size_t)255);

    hipMemsetAsync(bcnt, 0, (size_t)(NBCA + Na) * 4, stream);
    k_front   <<<NBLK, BINTHREADS, 0, stream>>>(src, dst, E, bcnt, deg, entries, NBC);
    k_sortgemm<<<NBC + NT, 256, 0, stream>>>(entries, bcnt, deg, x, W_conv,
                                             od, srcs, g, N, NBC);
    k_pull    <<<4096, 256, 0, stream>>>(g, od, srcs, b_conv, W_lin, b_lin, out, N);
}

// Round 13
// 172.909 us; speedup vs baseline: 1.2944x; 1.2944x over previous
//
#include <hip/hip_runtime.h>
#include <hip/hip_bf16.h>
#include <math.h>

#define F_IN   128
#define F_OUT  64
#define CHUNK  4096        // edges per bin block
#define BINTHREADS 1024    // bin block size (16 waves/block; round-11 win)
#define EPT    4           // edges per thread (CHUNK/BINTHREADS)
#define BSH    7           // bucket shift: 128 dsts per coarse bucket
#define CAP    3072        // per-bucket capacity (validated rounds 5-12)
#define NBCA   1024        // bucket array alignment

typedef short bf16x8 __attribute__((ext_vector_type(8)));
typedef float f32x4  __attribute__((ext_vector_type(4)));

__device__ __forceinline__ unsigned short f2bf(float f) {
    union { float f; unsigned int i; } c; c.f = f;
    unsigned int r = c.i + 0x7FFFu + ((c.i >> 16) & 1u);   // RNE
    return (unsigned short)(r >> 16);
}
__device__ __forceinline__ unsigned int pk2bf(float a, float b) {
    __hip_bfloat162 p = __float22bfloat162_rn(make_float2(a, b));  // v_cvt_pk_bf16_f32
    union { __hip_bfloat162 h; unsigned int u; } c; c.h = p; return c.u;
}
__device__ __forceinline__ float u_lo(unsigned int u) {
    union { unsigned int i; float f; } c; c.i = u << 16; return c.f;
}
__device__ __forceinline__ float u_hi(unsigned int u) {
    union { unsigned int i; float f; } c; c.i = u & 0xFFFF0000u; return c.f;
}

// ---- K1: binning. 1024 threads/block (16 waves; round-11 TLP win).
// LDS hist + block-aggregated global reserve + scatter. NO per-edge global
// atomics (rounds 3/5/12: those cost 60-500 us in every form tried).
__global__ __launch_bounds__(BINTHREADS) void k_bin(
    const int* __restrict__ src, const int* __restrict__ dst, int E,
    unsigned int* __restrict__ bcnt, unsigned int* __restrict__ entries, int NBC) {
    __shared__ int hist[NBCA];
    __shared__ int gbase[NBCA];
    __shared__ int lcur[NBCA];
    const int tid = threadIdx.x;
    const int e0 = blockIdx.x * CHUNK;

    for (int c = tid; c < NBCA; c += BINTHREADS) { hist[c] = 0; lcur[c] = 0; }
    __syncthreads();

    int dv[EPT], sv[EPT];
    #pragma unroll
    for (int j = 0; j < EPT; ++j) {
        int e = e0 + j * BINTHREADS + tid;
        if (e < E) {
            dv[j] = dst[e];
            sv[j] = src[e];
            atomicAdd(&hist[dv[j] >> BSH], 1);     // LDS atomic
        } else dv[j] = -1;
    }
    __syncthreads();

    for (int c = tid; c < NBC; c += BINTHREADS) {
        int h = hist[c];
        gbase[c] = h ? (int)atomicAdd(&bcnt[c], (unsigned int)h) : 0;
    }
    __syncthreads();

    #pragma unroll
    for (int j = 0; j < EPT; ++j) {
        if (dv[j] >= 0) {
            int b = dv[j] >> BSH;
            int r = atomicAdd(&lcur[b], 1);        // LDS atomic
            entries[b * CAP + gbase[b] + r] =
                ((unsigned int)(dv[j] & 127) << 24) | (unsigned int)sv[j];
        }
    }
}

// ---- K2: per-bucket (128 dsts) counting sort, LDS-staged (round-6 exact) ----
__global__ __launch_bounds__(256) void k_sort(
    const unsigned int* __restrict__ entries, const unsigned int* __restrict__ bcnt,
    int2* __restrict__ od, unsigned int* __restrict__ srcs, int N) {
    __shared__ unsigned int le[CAP];
    __shared__ unsigned int ls[CAP];
    __shared__ int hist[128];
    __shared__ int curs[128];
    const int tid = threadIdx.x;
    const int b = blockIdx.x;
    const int base = b * CAP;
    const int cnt = min((int)bcnt[b], CAP);

    if (tid < 128) hist[tid] = 0;
    __syncthreads();
    for (int i = tid; i < cnt; i += 256) {
        unsigned int v = entries[base + i];
        le[i] = v;
        atomicAdd(&hist[v >> 24], 1);
    }
    __syncthreads();

    int cntv = (tid < 128) ? hist[tid] : 0;
    if (tid < 128) curs[tid] = cntv;
    __syncthreads();
    for (int off = 1; off < 128; off <<= 1) {
        int t = (tid >= off && tid < 128) ? curs[tid - off] : 0;
        __syncthreads();
        if (tid < 128) curs[tid] += t;
        __syncthreads();
    }
    if (tid < 128) {
        int excl = curs[tid] - cntv;
        int d = (b << BSH) + tid;
        if (d < N) od[d] = make_int2(base + excl, cntv);
        curs[tid] = excl;
    }
    __syncthreads();

    for (int i = tid; i < cnt; i += 256) {
        unsigned int v = le[i];
        int p = atomicAdd(&curs[v >> 24], 1);
        ls[p] = (v & 0xFFFFFFu) << 7;
    }
    __syncthreads();

    for (int i = tid; i < cnt; i += 256)
        srcs[base + i] = ls[i];
}

// ---- K3: MFMA GEMM: g = bf16( (x @ W^T) * rsqrt(deg[row]+1) ); g[N] = 0 ----
__global__ __launch_bounds__(256) void k_gemm(
    const float* __restrict__ x, const float* __restrict__ W,
    const int2* __restrict__ od, unsigned short* __restrict__ g, int N) {
    __shared__ unsigned short xs[64 * F_IN];
    __shared__ unsigned short Wsh[F_OUT * F_IN];
    __shared__ float dinvs[64];

    const int tid  = threadIdx.x;
    const int row0 = blockIdx.x * 64;

    {
        const float4* W4 = (const float4*)W;
        #pragma unroll
        for (int t = 0; t < 8; ++t) {
            int idx = t * 256 + tid;
            float4 v = W4[idx];
            *(uint2*)&Wsh[idx * 4] = make_uint2(pk2bf(v.x, v.y), pk2bf(v.z, v.w));
        }
    }
    {
        const float4* x4 = (const float4*)x;
        #pragma unroll
        for (int t = 0; t < 8; ++t) {
            int idx = t * 256 + tid;
            int r = idx >> 5;
            int grow = row0 + r;
            float4 v = make_float4(0.f, 0.f, 0.f, 0.f);
            if (grow < N) v = x4[(size_t)grow * 32 + (idx & 31)];
            *(uint2*)&xs[idx * 4] = make_uint2(pk2bf(v.x, v.y), pk2bf(v.z, v.w));
        }
    }
    if (tid < 64) {
        int grow = row0 + tid;
        float dvv = 1.0f;
        if (grow < N) dvv = rsqrtf((float)od[grow].y + 1.0f);
        dinvs[tid] = dvv;
    }
    __syncthreads();

    const int lane = tid & 63;
    const int wave = tid >> 6;
    const int m = lane & 15;
    const int q = lane >> 4;
    const int r0 = wave * 16;

    bf16x8 a[4];
    #pragma unroll
    for (int ks = 0; ks < 4; ++ks)
        a[ks] = *(const bf16x8*)&xs[(r0 + m) * F_IN + ks * 32 + q * 8];

    f32x4 acc[4] = {{0,0,0,0},{0,0,0,0},{0,0,0,0},{0,0,0,0}};
    #pragma unroll
    for (int ct = 0; ct < 4; ++ct) {
        #pragma unroll
        for (int ks = 0; ks < 4; ++ks) {
            bf16x8 b = *(const bf16x8*)&Wsh[(ct * 16 + m) * F_IN + ks * 32 + q * 8];
            acc[ct] = __builtin_amdgcn_mfma_f32_16x16x32_bf16(a[ks], b, acc[ct], 0, 0, 0);
        }
    }

    float dvv[4];
    #pragma unroll
    for (int reg = 0; reg < 4; ++reg)
        dvv[reg] = dinvs[r0 + q * 4 + reg];
    #pragma unroll
    for (int ct = 0; ct < 4; ++ct) {
        #pragma unroll
        for (int reg = 0; reg < 4; ++reg) {
            int grow = row0 + r0 + q * 4 + reg;
            // grow == N writes the zero sentinel row (acc==0 there)
            if (grow <= N)
                g[(size_t)grow * F_OUT + ct * 16 + m] = f2bf(acc[ct][reg] * dvv[reg]);
        }
    }
}

// ---- K4: pull aggregation + fused epilogue (exact round-6/8 body, 35.6 us) ----
__global__ __launch_bounds__(256) void k_pull(
    const unsigned short* __restrict__ g, const int2* __restrict__ od,
    const unsigned int* __restrict__ srcs,
    const float* __restrict__ b_conv, const float* __restrict__ W_lin,
    const float* __restrict__ b_lin, float* __restrict__ out, int N) {
    const int lane = threadIdx.x & 63;
    const int li   = lane & 15;        // feature-quad index
    const int grp  = lane >> 4;        // edge group 0..3
    const int wave   = (blockIdx.x * blockDim.x + threadIdx.x) >> 6;
    const int nwaves = (gridDim.x * blockDim.x) >> 6;

    const float4 wl = ((const float4*)W_lin)[li];
    const float4 bb = ((const float4*)b_conv)[li];
    const float  bl = b_lin[0];
    const char* gb = (const char*)g;
    const unsigned int lioff = ((unsigned int)li) << 3;   // byte offset in row
    const unsigned int sentb = ((unsigned int)N) << 7;    // zero-row byte offset

    for (int i = wave; i < N; i += nwaves) {
        int2 odv = od[i];
        int e0 = __builtin_amdgcn_readfirstlane(odv.x);
        int dg = __builtin_amdgcn_readfirstlane(odv.y);
        int full = dg >> 4;
        int rem  = dg & 15;

        // self loop: group 0 only (others add 0)
        uint2 us = *(const uint2*)(gb + ((((unsigned int)i) << 7) | lioff));
        float4 acc;
        acc.x = grp ? 0.f : u_lo(us.x);
        acc.y = grp ? 0.f : u_hi(us.x);
        acc.z = grp ? 0.f : u_lo(us.y);
        acc.w = grp ? 0.f : u_hi(us.y);

        const unsigned int* sp = srcs + e0 + grp;   // group-interleaved list
        for (int it = 0; it < full; ++it) {
            unsigned int off[4];
            #pragma unroll
            for (int t = 0; t < 4; ++t)
                off[t] = sp[4 * t];                 // immediate offsets 0,4,8,12
            uint2 u[4];
            #pragma unroll
            for (int t = 0; t < 4; ++t)
                u[t] = *(const uint2*)(gb + (size_t)(off[t] | lioff));
            #pragma unroll
            for (int t = 0; t < 4; ++t) {
                acc.x += u_lo(u[t].x); acc.y += u_hi(u[t].x);
                acc.z += u_lo(u[t].y); acc.w += u_hi(u[t].y);
            }
            sp += 16;
        }
        if (rem) {                                  // wave-uniform branch
            unsigned int off[4];
            #pragma unroll
            for (int t = 0; t < 4; ++t) {
                unsigned int o = sp[4 * t];         // in-bounds load, may be junk
                off[t] = (4 * t + grp < rem) ? o : sentb;   // junk never addressed
            }
            uint2 u[4];
            #pragma unroll
            for (int t = 0; t < 4; ++t)
                u[t] = *(const uint2*)(gb + (size_t)(off[t] | lioff));
            #pragma unroll
            for (int t = 0; t < 4; ++t) {
                acc.x += u_lo(u[t].x); acc.y += u_hi(u[t].x);
                acc.z += u_lo(u[t].y); acc.w += u_hi(u[t].y);
            }
        }

        // sum across the 4 edge groups (lane bits 4,5)
        #pragma unroll
        for (int mk = 16; mk <= 32; mk <<= 1) {
            acc.x += __shfl_xor(acc.x, mk, 64);
            acc.y += __shfl_xor(acc.y, mk, 64);
            acc.z += __shfl_xor(acc.z, mk, 64);
            acc.w += __shfl_xor(acc.w, mk, 64);
        }

        float dinv = rsqrtf((float)dg + 1.0f);
        float r0 = fmaxf(acc.x * dinv + bb.x, 0.f);
        float r1 = fmaxf(acc.y * dinv + bb.y, 0.f);
        float r2 = fmaxf(acc.z * dinv + bb.z, 0.f);
        float r3 = fmaxf(acc.w * dinv + bb.w, 0.f);
        float t = r0 * wl.x + r1 * wl.y + r2 * wl.z + r3 * wl.w;
        #pragma unroll
        for (int mk = 1; mk <= 8; mk <<= 1)         // reduce over li (bits 0..3)
            t += __shfl_xor(t, mk, 64);
        if (lane == 0)
            out[i] = 1.0f / (1.0f + expf(-(t + bl)));
    }
}

extern "C" void kernel_launch(void* const* d_in, const int* in_sizes, int n_in,
                              void* d_out, int out_size, void* d_ws, size_t ws_size,
                              hipStream_t stream) {
    const float* x      = (const float*)d_in[0];
    const int*   ei     = (const int*)d_in[1];
    const float* W_conv = (const float*)d_in[2];
    const float* b_conv = (const float*)d_in[3];
    const float* W_lin  = (const float*)d_in[4];
    const float* b_lin  = (const float*)d_in[5];

    const int N = in_sizes[0] / F_IN;     // 100000
    const int E = in_sizes[1] / 2;        // 1600000
    const int* src = ei;
    const int* dst = ei + E;
    float* out = (float*)d_out;

    const int NBC  = (N + 127) >> BSH;          // 782 coarse buckets
    const int NBLK = (E + CHUNK - 1) / CHUNK;   // 391 bin blocks
    const int Na   = NBC << BSH;

    // workspace layout (4-byte units), ~33 MB
    unsigned int* bcnt = (unsigned int*)d_ws;                    // [NBCA] (memset 0)
    int2* od = (int2*)(bcnt + NBCA);                             // [Na]
    unsigned int* entries = (unsigned int*)((int*)od + 2 * Na);  // [NBC*CAP]
    unsigned int* srcs = entries + (size_t)NBC * CAP;            // [NBC*CAP + 64]
    char* graw = (char*)(srcs + (size_t)NBC * CAP + 64);
    unsigned short* g = (unsigned short*)(((size_t)graw + 255) & ~(size_t)255);

    hipMemsetAsync(bcnt, 0, NBCA * 4, stream);
    k_bin  <<<NBLK, BINTHREADS, 0, stream>>>(src, dst, E, bcnt, entries, NBC);
    k_sort <<<NBC, 256, 0, stream>>>(entries, bcnt, od, srcs, N);
    k_gemm <<<(N + 64) / 64, 256, 0, stream>>>(x, W_conv, od, g, N);
    k_pull <<<4096, 256, 0, stream>>>(g, od, srcs, b_conv, W_lin, b_lin, out, N);
}